// Round 8
// baseline (316.540 us; speedup 1.0000x reference)
//
#include <hip/hip_runtime.h>
#include <math.h>

#define SCALE_ 0.08838834764831845f   // 1/sqrt(128)
#define MINV_  (-3.4028234663852886e38f)

typedef __bf16 bf16;
typedef bf16  bf16x4 __attribute__((ext_vector_type(4)));
typedef bf16  bf16x8 __attribute__((ext_vector_type(8)));
typedef float f32x4  __attribute__((ext_vector_type(4)));
typedef float f32x16 __attribute__((ext_vector_type(16)));
typedef float float4v __attribute__((ext_vector_type(4)));

#define LD8(p) (*(const bf16x8*)(p))

__device__ __forceinline__ f32x4 mfma16(bf16x8 a, bf16x8 b, f32x4 c) {
    return __builtin_amdgcn_mfma_f32_16x16x32_bf16(a, b, c, 0, 0, 0);
}
__device__ __forceinline__ f32x16 mfma32(bf16x8 a, bf16x8 b, f32x16 c) {
    return __builtin_amdgcn_mfma_f32_32x32x16_bf16(a, b, c, 0, 0, 0);
}

typedef const __attribute__((address_space(1))) void* gas_t;
typedef __attribute__((address_space(3))) void* sas_t;
__device__ __forceinline__ void gload_lds16(const void* g, void* l) {
    __builtin_amdgcn_global_load_lds((gas_t)g, (sas_t)l, 16, 0, 0);
}

// ---------------- fused prep: cast_hidden | transpose_cast(Wqkv,Wo) | bt1_kv+bias ----------------
__global__ __launch_bounds__(256) void prep_kernel(const float* __restrict__ hidden, bf16* __restrict__ A16,
                                                   const float* __restrict__ Wqkv, bf16* __restrict__ BT1,
                                                   const float* __restrict__ Wo, bf16* __restrict__ BT2,
                                                   const float* __restrict__ bqkv, float* __restrict__ bias1)
{
    int x = blockIdx.x;
    if (x < 8192) {
        // cast hidden -> bf16
        int i = (x * 256 + threadIdx.x) * 4;
        float4v v = *(const float4v*)(hidden + i);
        bf16x4 o; o.x = (bf16)v.x; o.y = (bf16)v.y; o.z = (bf16)v.z; o.w = (bf16)v.w;
        *(bf16x4*)(A16 + i) = o;
        return;
    }
    if (x < 16384) {
        // transpose+cast: z=0 -> Wqkv (stride 6144, qmap) into BT1; z=1 -> Wo into BT2
        __shared__ float tile[32][33];
        int t = x - 8192;
        int z = t >> 12;
        int tt = t & 4095;
        const float* W = z ? Wo : Wqkv;
        bf16* BT = z ? BT2 : BT1;
        int srcStride = z ? 2048 : 6144;
        int k0 = (tt & 63) * 32, n0 = (tt >> 6) * 32;
        int c = threadIdx.x & 31, r = threadIdx.x >> 5;   // r in 0..7
        int n = n0 + c;
        int src = z ? n : ((n >> 7) * 384 + (n & 127));
        #pragma unroll
        for (int rr = 0; rr < 32; rr += 8)
            tile[r + rr][c] = W[(size_t)(k0 + r + rr) * srcStride + src];
        __syncthreads();
        #pragma unroll
        for (int rr = 0; rr < 32; rr += 8)
            BT[(size_t)(n0 + r + rr) * 2048 + k0 + c] = (bf16)tile[c][r + rr];
        return;
    }
    int t = x - 16384;   // 0..512
    if (t == 512) {
        for (int c = threadIdx.x; c < 2304; c += 256) {
            if (c < 2048) bias1[c] = bqkv[(c >> 7) * 384 + (c & 127)];
            else {
                int j = c - 2048; float s = 0.f;
                for (int h = 0; h < 16; h++) s += bqkv[h * 384 + 128 + j];
                bias1[c] = s * 0.0625f;
            }
        }
        return;
    }
    // rows 2048..2303 of BT1: head-averaged k/v weight columns, 4 k-cols per block
    int k0 = t * 4;
    int j = threadIdx.x;            // 0..255
    float acc[4];
    #pragma unroll
    for (int k = 0; k < 4; k++) acc[k] = 0.f;
    for (int h = 0; h < 16; h++) {
        #pragma unroll
        for (int k = 0; k < 4; k++)
            acc[k] += Wqkv[(size_t)(k0 + k) * 6144 + h * 384 + 128 + j];
    }
    #pragma unroll
    for (int k = 0; k < 4; k++)
        BT1[(size_t)(2048 + j) * 2048 + k0 + k] = (bf16)(acc[k] * 0.0625f);
}

// ---------------- GEMM core: 128x128 tile, BK=64, DOUBLE-buffered LDS, counted-vmcnt pipeline ----
// r8: r1's counted-vmcnt dbuf K-loop (correctness harness-proven in r1) on the r5/r7 standalone
// kernels. Mechanism: at 576/512 blocks (~2.25/CU) implicit inter-block overlap is too thin to
// hide the vmcnt(0) barrier drain of the 2-barrier loop; vmcnt(8) keeps the next tile's 8 loads
// in flight across barriers. Epilogues byte-identical to r7 (r1-r5 lesson: epilogue perturbs
// whole-kernel codegen — standalone kernels only, no templates, no vv staging array).

#define GEMM_DB_PROLOGUE_AND_KLOOP                                                        \
    __shared__ __align__(16) bf16 As[2][128 * 64];                                        \
    __shared__ __align__(16) bf16 Bs[2][128 * 64];                                        \
    const int tid  = threadIdx.x;                                                         \
    const int wv   = tid >> 6, lane = tid & 63, l32 = lane & 31, half = lane >> 5;        \
    const int wrow = wv >> 1, wcol = wv & 1;                                              \
    const int m0 = blockIdx.y * 128, n0 = blockIdx.x * 128;                               \
    int rowS[4], colS[4];                                                                 \
    _Pragma("unroll")                                                                     \
    for (int j = 0; j < 4; j++) {                                                         \
        int flat = (wv * 4 + j) * 64 + lane;                                              \
        int row = flat >> 3, cp = flat & 7;                                               \
        rowS[j] = row;                                                                    \
        colS[j] = (cp ^ (row & 7)) * 8;                                                   \
    }                                                                                     \
    const int nt = K >> 6;                                                                \
    auto stage = [&](int t, int bsel) {      /* 8 global_load_lds per wave per call */    \
        int kk = t << 6;                                                                  \
        _Pragma("unroll")                                                                 \
        for (int j = 0; j < 4; j++) {                                                     \
            gload_lds16(A  + (size_t)(m0 + rowS[j]) * K + kk + colS[j], &As[bsel][(wv * 4 + j) * 512]); \
            gload_lds16(BT + (size_t)(n0 + rowS[j]) * K + kk + colS[j], &Bs[bsel][(wv * 4 + j) * 512]); \
        }                                                                                 \
    };                                                                                    \
    f32x16 acc[2][2];                                                                     \
    _Pragma("unroll")                                                                     \
    for (int i = 0; i < 2; i++)                                                           \
        _Pragma("unroll")                                                                 \
        for (int j = 0; j < 2; j++)                                                       \
            _Pragma("unroll")                                                             \
            for (int r = 0; r < 16; r++) acc[i][j][r] = 0.f;                              \
    stage(0, 0);                                                                          \
    stage(1, 1);                                                                          \
    for (int t = 0; t < nt; ++t) {                                                        \
        const int cur = t & 1;                                                            \
        if (t < nt - 1) asm volatile("s_waitcnt vmcnt(8)" ::: "memory");                  \
        else            asm volatile("s_waitcnt vmcnt(0)" ::: "memory");                  \
        __builtin_amdgcn_s_barrier();                                                     \
        asm volatile("" ::: "memory");                                                    \
        const bf16* Ab = &As[cur][0];                                                     \
        const bf16* Bb = &Bs[cur][0];                                                     \
        bf16x8 af[2][4], bfr[2][4];                                                       \
        _Pragma("unroll")                                                                 \
        for (int mt = 0; mt < 2; mt++) {                                                  \
            int row = wrow * 64 + mt * 32 + l32;                                          \
            _Pragma("unroll")                                                             \
            for (int k16 = 0; k16 < 4; k16++) {                                           \
                int lc = k16 * 2 + half;                                                  \
                af[mt][k16] = LD8(&Ab[row * 64 + ((lc ^ (row & 7)) * 8)]);                \
            }                                                                             \
        }                                                                                 \
        _Pragma("unroll")                                                                 \
        for (int nt2 = 0; nt2 < 2; nt2++) {                                               \
            int row = wcol * 64 + nt2 * 32 + l32;                                         \
            _Pragma("unroll")                                                             \
            for (int k16 = 0; k16 < 4; k16++) {                                           \
                int lc = k16 * 2 + half;                                                  \
                bfr[nt2][k16] = LD8(&Bb[row * 64 + ((lc ^ (row & 7)) * 8)]);              \
            }                                                                             \
        }                                                                                 \
        _Pragma("unroll")                                                                 \
        for (int k16 = 0; k16 < 4; k16++)                                                 \
            _Pragma("unroll")                                                             \
            for (int mt = 0; mt < 2; mt++)                                                \
                _Pragma("unroll")                                                         \
                for (int nt2 = 0; nt2 < 2; nt2++)                                         \
                    acc[mt][nt2] = mfma32(af[mt][k16], bfr[nt2][k16], acc[mt][nt2]);      \
        asm volatile("" ::: "memory");                                                    \
        __builtin_amdgcn_s_barrier();                                                     \
        asm volatile("" ::: "memory");                                                    \
        if (t + 2 < nt) stage(t + 2, cur);                                                \
    }

// gemm1: C1 = A16 . BT1^T + bias, bf16 out, rotary fused per-r inline (no staging array)
__global__ __launch_bounds__(256) void gemm_rot_kernel(const bf16* __restrict__ A, const bf16* __restrict__ BT,
                                                       const float* __restrict__ bias, bf16* __restrict__ C,
                                                       int M, int N, int K)
{
    GEMM_DB_PROLOGUE_AND_KLOOP

    #pragma unroll
    for (int mt = 0; mt < 2; mt++) {
        #pragma unroll
        for (int nt2 = 0; nt2 < 2; nt2++) {
            int n = n0 + wcol * 64 + nt2 * 32 + l32;
            float bn = bias[n];
            const bool rot = (wcol == 0) && (nt2 == 0) && (n0 <= 2048);  // wave-uniform
            float inv = rot ? __expf(-0.575646273248511f * (float)(l32 & 15)) : 0.f;
            #pragma unroll
            for (int r = 0; r < 16; r++) {
                int m = m0 + wrow * 64 + mt * 32 + (r & 3) + 8 * (r >> 2) + 4 * half;
                float v = acc[mt][nt2][r] + bn;
                if (rot) {
                    float ang = (float)(m & 2047) * inv;
                    float cs, sn;
                    __sincosf(ang, &sn, &cs);
                    float pv = __shfl_xor(v, 16, 64);
                    v = (l32 < 16) ? (v * cs - pv * sn) : (v * cs + pv * sn);
                }
                C[(size_t)m * N + n] = (bf16)v;
            }
        }
    }
}

// gemm2: out = attnb . BT2^T + bias, float out — direct per-r store epilogue
__global__ __launch_bounds__(256) void gemm_out_kernel(const bf16* __restrict__ A, const bf16* __restrict__ BT,
                                                       const float* __restrict__ bias, float* __restrict__ C,
                                                       int M, int N, int K)
{
    GEMM_DB_PROLOGUE_AND_KLOOP

    #pragma unroll
    for (int mt = 0; mt < 2; mt++) {
        #pragma unroll
        for (int nt2 = 0; nt2 < 2; nt2++) {
            int n = n0 + wcol * 64 + nt2 * 32 + l32;
            float bn = bias[n];
            #pragma unroll
            for (int r = 0; r < 16; r++) {
                int m = m0 + wrow * 64 + mt * 32 + (r & 3) + 8 * (r >> 2) + 4 * half;
                C[(size_t)m * N + n] = acc[mt][nt2][r] + bn;
            }
        }
    }
}

// ---------------- pretile K/V into MFMA fragment order; self-contained (vmT-free) ----------------
__global__ __launch_bounds__(256) void pretile_kernel(const bf16* __restrict__ C1, const int* __restrict__ gidx,
                                                      bf16* __restrict__ KF, bf16* __restrict__ VF)
{
    __shared__ bf16 Vt[64][130];
    const int c = blockIdx.x, b = blockIdx.y;
    const bool isGlob = (c == 32);
    const int tid = threadIdx.x;

    // stage V tile: 64 rows x 128 cols (each thread: 1 row-quarter = 32 cols)
    {
        int row = tid >> 2, cb = (tid & 3) * 32;
        int pos = isGlob ? gidx[b * 64 + row] : (c * 64 + row);
        const bf16* src = C1 + (size_t)(b * 2048 + pos) * 2304 + 2176 + cb;
        #pragma unroll
        for (int k = 0; k < 4; k++)
            *(bf16x8*)&Vt[row][cb + k * 8] = LD8(src + k * 8);
    }
    __syncthreads();

    // KF frags: fi = t*4+ks; direct from C1
    #pragma unroll
    for (int i = 0; i < 4; i++) {
        int sid = tid + i * 256;
        int lane = sid & 63, fi = sid >> 6;
        int l16 = lane & 15, quad = lane >> 4;
        int t = fi >> 2, ks = fi & 3;
        int pos = isGlob ? gidx[b * 64 + t * 16 + l16] : (c * 64 + t * 16 + l16);
        const bf16* src = C1 + (size_t)(b * 2048 + pos) * 2304 + 2048 + ks * 32 + quad * 8;
        *(bf16x8*)&KF[((size_t)(b * 33 + c) * 16 + fi) * 512 + lane * 8] = LD8(src);
    }

    // VF frags: fi = dt*2+ks2; transpose-read from LDS
    #pragma unroll
    for (int i = 0; i < 4; i++) {
        int sid = tid + i * 256;
        int lane = sid & 63, fi = sid >> 6;
        int l16 = lane & 15, quad = lane >> 4;
        int dt = fi >> 1, ks2 = fi & 1;
        int d = dt * 16 + l16;
        bf16x8 v;
        #pragma unroll
        for (int j = 0; j < 8; j++)
            v[j] = Vt[ks2 * 32 + quad * 8 + j][d];
        *(bf16x8*)&VF[((size_t)(b * 33 + c) * 16 + fi) * 512 + lane * 8] = v;
    }
}

#define PSTRIDE 88

// ---------------- attention, first WIN=256 queries (causal): wave-autonomous, pretiled frags ----------------
__device__ __forceinline__ void attn0_body(int bx, int h, int b, bf16* Pw,
                                           const bf16* __restrict__ C1, const bf16* __restrict__ KF,
                                           const bf16* __restrict__ VF, const float* __restrict__ mask,
                                           bf16* __restrict__ attn)
{
    const int tid = threadIdx.x, wv = tid >> 6, lane = tid & 63, quad = lane >> 4, l16 = lane & 15;
    const int q0 = (bx * 4 + wv) * 16;

    bf16x8 af[4];
    const bf16* qbase = C1 + (size_t)(b * 2048 + q0 + l16) * 2304 + h * 128;
    #pragma unroll
    for (int ks = 0; ks < 4; ks++) af[ks] = LD8(qbase + ks * 32 + quad * 8);

    f32x4 m_run = (f32x4){MINV_, MINV_, MINV_, MINV_};
    f32x4 l_run = (f32x4){0.f, 0.f, 0.f, 0.f};
    f32x4 O[8];
    #pragma unroll
    for (int dt = 0; dt < 8; dt++) O[dt] = (f32x4){0.f, 0.f, 0.f, 0.f};

    for (int c = 0; c <= bx; c++) {
        const bf16* KFc = KF + ((size_t)(b * 33 + c) * 16) * 512;
        const bf16* VFc = VF + ((size_t)(b * 33 + c) * 16) * 512;

        f32x4 acc[4];
        #pragma unroll
        for (int t = 0; t < 4; t++) acc[t] = (f32x4){0.f, 0.f, 0.f, 0.f};
        #pragma unroll
        for (int t = 0; t < 4; t++)
            #pragma unroll
            for (int ks = 0; ks < 4; ks++)
                acc[t] = mfma16(af[ks], LD8(KFc + (size_t)(t * 4 + ks) * 512 + lane * 8), acc[t]);

        float sv[4][4];
        #pragma unroll
        for (int t = 0; t < 4; t++) {
            int key = c * 64 + t * 16 + l16;
            float addv = mask[b * 2048 + key];
            #pragma unroll
            for (int r = 0; r < 4; r++) {
                int q = q0 + quad * 4 + r;
                sv[t][r] = (key <= q) ? (acc[t][r] * SCALE_ + addv) : MINV_;
            }
        }

        f32x4 cm;
        #pragma unroll
        for (int r = 0; r < 4; r++) cm[r] = fmaxf(fmaxf(sv[0][r], sv[1][r]), fmaxf(sv[2][r], sv[3][r]));
        #pragma unroll
        for (int ms = 1; ms < 16; ms <<= 1)
            #pragma unroll
            for (int r = 0; r < 4; r++) cm[r] = fmaxf(cm[r], __shfl_xor(cm[r], ms, 64));

        f32x4 nm, alpha;
        #pragma unroll
        for (int r = 0; r < 4; r++) { nm[r] = fmaxf(m_run[r], cm[r]); alpha[r] = __expf(m_run[r] - nm[r]); }

        float pv[4][4];
        f32x4 cs = (f32x4){0.f, 0.f, 0.f, 0.f};
        #pragma unroll
        for (int t = 0; t < 4; t++)
            #pragma unroll
            for (int r = 0; r < 4; r++) {
                pv[t][r] = __expf(sv[t][r] - nm[r]);   // MINV_ underflows to 0
                cs[r] += pv[t][r];
            }
        #pragma unroll
        for (int ms = 1; ms < 16; ms <<= 1)
            #pragma unroll
            for (int r = 0; r < 4; r++) cs[r] += __shfl_xor(cs[r], ms, 64);

        m_run = nm;
        #pragma unroll
        for (int r = 0; r < 4; r++) l_run[r] = l_run[r] * alpha[r] + cs[r];
        #pragma unroll
        for (int dt = 0; dt < 8; dt++)
            #pragma unroll
            for (int r = 0; r < 4; r++) O[dt][r] *= alpha[r];

        #pragma unroll
        for (int t = 0; t < 4; t++)
            #pragma unroll
            for (int r = 0; r < 4; r++)
                Pw[(quad * 4 + r) * PSTRIDE + t * 16 + l16] = (bf16)pv[t][r];
        bf16x8 pa0 = LD8(&Pw[l16 * PSTRIDE + quad * 8]);
        bf16x8 pa1 = LD8(&Pw[l16 * PSTRIDE + 32 + quad * 8]);

        #pragma unroll
        for (int dt = 0; dt < 8; dt++) {
            O[dt] = mfma16(pa0, LD8(VFc + (size_t)(dt * 2 + 0) * 512 + lane * 8), O[dt]);
            O[dt] = mfma16(pa1, LD8(VFc + (size_t)(dt * 2 + 1) * 512 + lane * 8), O[dt]);
        }
    }

    f32x4 invl;
    #pragma unroll
    for (int r = 0; r < 4; r++) invl[r] = 1.0f / l_run[r];
    #pragma unroll
    for (int dt = 0; dt < 8; dt++)
        #pragma unroll
        for (int r = 0; r < 4; r++) {
            int q = q0 + quad * 4 + r;
            attn[(size_t)(b * 2048 + q) * 2048 + h * 128 + dt * 16 + l16] = (bf16)(O[dt][r] * invl[r]);
        }
}

// ---------------- attention steps: barrier-free, wave-autonomous, pretiled frags ----------------
__device__ __forceinline__ void attn_steps_body(int sb, int b, bf16* Pw,
                                                const bf16* __restrict__ C1, const bf16* __restrict__ KF,
                                                const bf16* __restrict__ VF, const float* __restrict__ mask,
                                                const int* __restrict__ gidx, bf16* __restrict__ attn)
{
    const int tid = threadIdx.x, wv = tid >> 6, lane = tid & 63, quad = lane >> 4, l16 = lane & 15;
    const int step = sb * 4 + wv, p = 256 + step;

    bf16x8 af[4];
    const bf16* qrow = C1 + (size_t)(b * 2048 + p) * 2304;
    #pragma unroll
    for (int ks = 0; ks < 4; ks++) af[ks] = LD8(qrow + l16 * 128 + ks * 32 + quad * 8);

    int gix[4];
    #pragma unroll
    for (int t = 0; t < 4; t++) gix[t] = gidx[b * 64 + t * 16 + l16];

    f32x4 m_run = (f32x4){MINV_, MINV_, MINV_, MINV_};
    f32x4 l_run = (f32x4){0.f, 0.f, 0.f, 0.f};
    f32x4 O[8];
    #pragma unroll
    for (int dt = 0; dt < 8; dt++) O[dt] = (f32x4){0.f, 0.f, 0.f, 0.f};

    const int c0 = (step + 1) >> 6;

    for (int iter = 0; iter < 6; iter++) {
        int c;
        bool isGlob = (iter == 0);
        if (isGlob) c = 32;
        else { c = c0 + iter - 1; if (c > 31) break; }

        const bf16* KFc = KF + ((size_t)(b * 33 + c) * 16) * 512;
        const bf16* VFc = VF + ((size_t)(b * 33 + c) * 16) * 512;

        f32x4 acc[4];
        #pragma unroll
        for (int t = 0; t < 4; t++) acc[t] = (f32x4){0.f, 0.f, 0.f, 0.f};
        #pragma unroll
        for (int t = 0; t < 4; t++)
            #pragma unroll
            for (int ks = 0; ks < 4; ks++)
                acc[t] = mfma16(af[ks], LD8(KFc + (size_t)(t * 4 + ks) * 512 + lane * 8), acc[t]);

        float sv[4][4];
        bool vld[4];
        #pragma unroll
        for (int t = 0; t < 4; t++) {
            float addv = 0.f;
            if (isGlob) vld[t] = gix[t] < step;
            else {
                int pos = c * 64 + t * 16 + l16;
                vld[t] = (unsigned)(pos - step - 1) < 256u;
                addv = mask[b * 2048 + pos];
            }
            #pragma unroll
            for (int r = 0; r < 4; r++) sv[t][r] = vld[t] ? (acc[t][r] * SCALE_ + addv) : MINV_;
        }

        f32x4 cm;
        #pragma unroll
        for (int r = 0; r < 4; r++) cm[r] = fmaxf(fmaxf(sv[0][r], sv[1][r]), fmaxf(sv[2][r], sv[3][r]));
        #pragma unroll
        for (int ms = 1; ms < 16; ms <<= 1)
            #pragma unroll
            for (int r = 0; r < 4; r++) cm[r] = fmaxf(cm[r], __shfl_xor(cm[r], ms, 64));

        f32x4 nm, alpha;
        #pragma unroll
        for (int r = 0; r < 4; r++) { nm[r] = fmaxf(m_run[r], cm[r]); alpha[r] = __expf(m_run[r] - nm[r]); }

        float pv[4][4];
        f32x4 cs = (f32x4){0.f, 0.f, 0.f, 0.f};
        #pragma unroll
        for (int t = 0; t < 4; t++)
            #pragma unroll
            for (int r = 0; r < 4; r++) {
                pv[t][r] = vld[t] ? __expf(sv[t][r] - nm[r]) : 0.f;
                cs[r] += pv[t][r];
            }
        #pragma unroll
        for (int ms = 1; ms < 16; ms <<= 1)
            #pragma unroll
            for (int r = 0; r < 4; r++) cs[r] += __shfl_xor(cs[r], ms, 64);

        m_run = nm;
        #pragma unroll
        for (int r = 0; r < 4; r++) l_run[r] = l_run[r] * alpha[r] + cs[r];
        #pragma unroll
        for (int dt = 0; dt < 8; dt++)
            #pragma unroll
            for (int r = 0; r < 4; r++) O[dt][r] *= alpha[r];

        #pragma unroll
        for (int t = 0; t < 4; t++)
            #pragma unroll
            for (int r = 0; r < 4; r++)
                Pw[(quad * 4 + r) * PSTRIDE + t * 16 + l16] = (bf16)pv[t][r];
        bf16x8 pa0 = LD8(&Pw[l16 * PSTRIDE + quad * 8]);
        bf16x8 pa1 = LD8(&Pw[l16 * PSTRIDE + 32 + quad * 8]);

        #pragma unroll
        for (int dt = 0; dt < 8; dt++) {
            O[dt] = mfma16(pa0, LD8(VFc + (size_t)(dt * 2 + 0) * 512 + lane * 8), O[dt]);
            O[dt] = mfma16(pa1, LD8(VFc + (size_t)(dt * 2 + 1) * 512 + lane * 8), O[dt]);
        }
    }

    f32x4 invl;
    #pragma unroll
    for (int r = 0; r < 4; r++) invl[r] = 1.0f / l_run[r];
    #pragma unroll
    for (int dt = 0; dt < 8; dt++)
        #pragma unroll
        for (int r = 0; r < 4; r++) {
            int h = quad * 4 + r;
            attn[(size_t)(b * 2048 + p) * 2048 + h * 128 + dt * 16 + l16] = (bf16)(O[dt][r] * invl[r]);
        }
}

// merged attention launch: x<448 -> steps (sb=x); x>=448 -> attn0 (bi=x-448: bx=bi>>4, h=bi&15)
__global__ __launch_bounds__(256) void attn_all_kernel(const bf16* __restrict__ C1, const bf16* __restrict__ KF,
                                                       const bf16* __restrict__ VF, const float* __restrict__ mask,
                                                       const int* __restrict__ gidx, bf16* __restrict__ attn)
{
    __shared__ __align__(16) bf16 Ps[4 * 16 * PSTRIDE];
    const int wv = threadIdx.x >> 6;
    bf16* Pw = &Ps[wv * (16 * PSTRIDE)];
    if (blockIdx.x < 448) {
        attn_steps_body(blockIdx.x, blockIdx.y, Pw, C1, KF, VF, mask, gidx, attn);
    } else {
        int bi = blockIdx.x - 448;
        attn0_body(bi >> 4, bi & 15, blockIdx.y, Pw, C1, KF, VF, mask, attn);
    }
}

// ---------------- launch ----------------
extern "C" void kernel_launch(void* const* d_in, const int* in_sizes, int n_in,
                              void* d_out, int out_size, void* d_ws, size_t ws_size,
                              hipStream_t stream)
{
    const float* hidden = (const float*)d_in[0];
    const float* amask  = (const float*)d_in[1];
    const int*   gidx   = (const int*)d_in[2];
    const float* Wqkv   = (const float*)d_in[3];
    const float* bqkv   = (const float*)d_in[4];
    const float* Wo     = (const float*)d_in[5];
    const float* bo     = (const float*)d_in[6];

    char* ws = (char*)d_ws;
    size_t off = 0;
    auto take = [&](size_t bytes) -> char* {
        char* p = ws + off;
        off = (off + bytes + 255) & ~(size_t)255;
        return p;
    };
    bf16*  A16   = (bf16*)take(4096ull * 2048 * 2);   // hidden, bf16
    bf16*  BT1   = (bf16*)take(2304ull * 2048 * 2);   // [q cols | k-avg | v-avg]^T
    bf16*  BT2   = (bf16*)take(2048ull * 2048 * 2);   // Wo^T
    bf16*  C1    = (bf16*)take(4096ull * 2304 * 2);   // q(2048) | k_mean(128) | v_mean(128)
    bf16*  KF    = (bf16*)take(2ull * 33 * 16 * 512 * 2);
    bf16*  VF    = (bf16*)take(2ull * 33 * 16 * 512 * 2);
    bf16*  attnb = (bf16*)take(4096ull * 2048 * 2);
    float* bias1 = (float*)take(2304 * 4);

    prep_kernel<<<16897, 256, 0, stream>>>(hidden, A16, Wqkv, BT1, Wo, BT2, bqkv, bias1);

    gemm_rot_kernel<<<dim3(18, 32), 256, 0, stream>>>(A16, BT1, bias1, C1, 4096, 2304, 2048);

    pretile_kernel<<<dim3(33, 2), 256, 0, stream>>>(C1, gidx, KF, VF);

    attn_all_kernel<<<dim3(512, 2), 256, 0, stream>>>(C1, KF, VF, amask, gidx, attnb);

    gemm_out_kernel<<<dim3(16, 32), 256, 0, stream>>>(attnb, BT2, bo, (float*)d_out, 4096, 2048, 2048);

    (void)in_sizes; (void)n_in; (void)out_size; (void)ws_size;
}

// Round 9
// 293.281 us; speedup vs baseline: 1.0793x; 1.0793x over previous
//
#include <hip/hip_runtime.h>
#include <math.h>

#define SCALE_ 0.08838834764831845f   // 1/sqrt(128)
#define MINV_  (-3.4028234663852886e38f)

typedef __bf16 bf16;
typedef bf16  bf16x4 __attribute__((ext_vector_type(4)));
typedef bf16  bf16x8 __attribute__((ext_vector_type(8)));
typedef float f32x4  __attribute__((ext_vector_type(4)));
typedef float f32x16 __attribute__((ext_vector_type(16)));
typedef float float4v __attribute__((ext_vector_type(4)));

#define LD8(p) (*(const bf16x8*)(p))

__device__ __forceinline__ f32x4 mfma16(bf16x8 a, bf16x8 b, f32x4 c) {
    return __builtin_amdgcn_mfma_f32_16x16x32_bf16(a, b, c, 0, 0, 0);
}
__device__ __forceinline__ f32x16 mfma32(bf16x8 a, bf16x8 b, f32x16 c) {
    return __builtin_amdgcn_mfma_f32_32x32x16_bf16(a, b, c, 0, 0, 0);
}

typedef const __attribute__((address_space(1))) void* gas_t;
typedef __attribute__((address_space(3))) void* sas_t;
__device__ __forceinline__ void gload_lds16(const void* g, void* l) {
    __builtin_amdgcn_global_load_lds((gas_t)g, (sas_t)l, 16, 0, 0);
}

// ---------------- fused prep: bt1_kv+bias | cast_hidden | transpose_cast(Wqkv,Wo) ----------------
// r9: kv-reduction blocks (longest serial critical path) dispatch FIRST so they start while
// the streaming cast/transpose blocks fill the machine behind them.
__global__ __launch_bounds__(256) void prep_kernel(const float* __restrict__ hidden, bf16* __restrict__ A16,
                                                   const float* __restrict__ Wqkv, bf16* __restrict__ BT1,
                                                   const float* __restrict__ Wo, bf16* __restrict__ BT2,
                                                   const float* __restrict__ bqkv, float* __restrict__ bias1)
{
    int x = blockIdx.x;
    if (x < 512) {
        // rows 2048..2303 of BT1: head-averaged k/v weight columns, 4 k-cols per block
        int k0 = x * 4;
        int j = threadIdx.x;            // 0..255
        float acc[4];
        #pragma unroll
        for (int k = 0; k < 4; k++) acc[k] = 0.f;
        for (int h = 0; h < 16; h++) {
            #pragma unroll
            for (int k = 0; k < 4; k++)
                acc[k] += Wqkv[(size_t)(k0 + k) * 6144 + h * 384 + 128 + j];
        }
        #pragma unroll
        for (int k = 0; k < 4; k++)
            BT1[(size_t)(2048 + j) * 2048 + k0 + k] = (bf16)(acc[k] * 0.0625f);
        return;
    }
    if (x == 512) {
        for (int c = threadIdx.x; c < 2304; c += 256) {
            if (c < 2048) bias1[c] = bqkv[(c >> 7) * 384 + (c & 127)];
            else {
                int j = c - 2048; float s = 0.f;
                for (int h = 0; h < 16; h++) s += bqkv[h * 384 + 128 + j];
                bias1[c] = s * 0.0625f;
            }
        }
        return;
    }
    if (x < 8705) {
        // cast hidden -> bf16 (8192 blocks)
        int i = ((x - 513) * 256 + threadIdx.x) * 4;
        float4v v = *(const float4v*)(hidden + i);
        bf16x4 o; o.x = (bf16)v.x; o.y = (bf16)v.y; o.z = (bf16)v.z; o.w = (bf16)v.w;
        *(bf16x4*)(A16 + i) = o;
        return;
    }
    // transpose+cast (8192 blocks): z=0 -> Wqkv (stride 6144, qmap) into BT1; z=1 -> Wo into BT2
    __shared__ float tile[32][33];
    int t = x - 8705;
    int z = t >> 12;
    int tt = t & 4095;
    const float* W = z ? Wo : Wqkv;
    bf16* BT = z ? BT2 : BT1;
    int srcStride = z ? 2048 : 6144;
    int k0 = (tt & 63) * 32, n0 = (tt >> 6) * 32;
    int c = threadIdx.x & 31, r = threadIdx.x >> 5;   // r in 0..7
    int n = n0 + c;
    int src = z ? n : ((n >> 7) * 384 + (n & 127));
    #pragma unroll
    for (int rr = 0; rr < 32; rr += 8)
        tile[r + rr][c] = W[(size_t)(k0 + r + rr) * srcStride + src];
    __syncthreads();
    #pragma unroll
    for (int rr = 0; rr < 32; rr += 8)
        BT[(size_t)(n0 + r + rr) * 2048 + k0 + c] = (bf16)tile[c][r + rr];
}

// ---------------- GEMM core (m97 structure, 32x32x16 MFMA) — SETTLED, do not restructure ----------
// 128x128 tile, BK=64, single 32KB LDS, 2-barrier K-loop. Measured verdicts on this shape:
//   r3: XCD swizzle HURT (-47%: latency-bound, L2->L3 shift).
//   r5: template/vv-array epilogue HURT (+25us: VGPR 80->88, K-loop rescheduled).
//   r8: dbuf+counted-vmcnt HURT (+16us: 64KB LDS halves residency; m132 confirmed).
// This exact form = 63us @ VGPR 80, Occ 18%, MfmaUtil 24%.

#define GEMM_PROLOGUE_AND_KLOOP                                                           \
    __shared__ __align__(16) bf16 As[128 * 64];                                           \
    __shared__ __align__(16) bf16 Bs[128 * 64];                                           \
    const int tid  = threadIdx.x;                                                         \
    const int wv   = tid >> 6, lane = tid & 63, l32 = lane & 31, half = lane >> 5;        \
    const int wrow = wv >> 1, wcol = wv & 1;                                              \
    const int m0 = blockIdx.y * 128, n0 = blockIdx.x * 128;                               \
    int rowS[4], colS[4];                                                                 \
    _Pragma("unroll")                                                                     \
    for (int j = 0; j < 4; j++) {                                                         \
        int flat = (wv * 4 + j) * 64 + lane;                                              \
        int row = flat >> 3, cp = flat & 7;                                               \
        rowS[j] = row;                                                                    \
        colS[j] = (cp ^ (row & 7)) * 8;                                                   \
    }                                                                                     \
    f32x16 acc[2][2];                                                                     \
    _Pragma("unroll")                                                                     \
    for (int i = 0; i < 2; i++)                                                           \
        _Pragma("unroll")                                                                 \
        for (int j = 0; j < 2; j++)                                                       \
            _Pragma("unroll")                                                             \
            for (int r = 0; r < 16; r++) acc[i][j][r] = 0.f;                              \
    for (int kk = 0; kk < K; kk += 64) {                                                  \
        __syncthreads();                                                                  \
        _Pragma("unroll")                                                                 \
        for (int j = 0; j < 4; j++) {                                                     \
            gload_lds16(A  + (size_t)(m0 + rowS[j]) * K + kk + colS[j], &As[(wv * 4 + j) * 512]); \
            gload_lds16(BT + (size_t)(n0 + rowS[j]) * K + kk + colS[j], &Bs[(wv * 4 + j) * 512]); \
        }                                                                                 \
        __syncthreads();                                                                  \
        bf16x8 af[2][4], bfr[2][4];                                                       \
        _Pragma("unroll")                                                                 \
        for (int mt = 0; mt < 2; mt++) {                                                  \
            int row = wrow * 64 + mt * 32 + l32;                                          \
            _Pragma("unroll")                                                             \
            for (int k16 = 0; k16 < 4; k16++) {                                           \
                int lc = k16 * 2 + half;                                                  \
                af[mt][k16] = LD8(&As[row * 64 + ((lc ^ (row & 7)) * 8)]);                \
            }                                                                             \
        }                                                                                 \
        _Pragma("unroll")                                                                 \
        for (int nt = 0; nt < 2; nt++) {                                                  \
            int row = wcol * 64 + nt * 32 + l32;                                          \
            _Pragma("unroll")                                                             \
            for (int k16 = 0; k16 < 4; k16++) {                                           \
                int lc = k16 * 2 + half;                                                  \
                bfr[nt][k16] = LD8(&Bs[row * 64 + ((lc ^ (row & 7)) * 8)]);               \
            }                                                                             \
        }                                                                                 \
        _Pragma("unroll")                                                                 \
        for (int k16 = 0; k16 < 4; k16++)                                                 \
            _Pragma("unroll")                                                             \
            for (int mt = 0; mt < 2; mt++)                                                \
                _Pragma("unroll")                                                         \
                for (int nt = 0; nt < 2; nt++)                                            \
                    acc[mt][nt] = mfma32(af[mt][k16], bfr[nt][k16], acc[mt][nt]);         \
    }

// gemm1: C1 = A16 . BT1^T + bias, bf16 out, rotary fused per-r inline (no staging array)
__global__ __launch_bounds__(256) void gemm_rot_kernel(const bf16* __restrict__ A, const bf16* __restrict__ BT,
                                                       const float* __restrict__ bias, bf16* __restrict__ C,
                                                       int M, int N, int K)
{
    GEMM_PROLOGUE_AND_KLOOP

    #pragma unroll
    for (int mt = 0; mt < 2; mt++) {
        #pragma unroll
        for (int nt = 0; nt < 2; nt++) {
            int n = n0 + wcol * 64 + nt * 32 + l32;
            float bn = bias[n];
            const bool rot = (wcol == 0) && (nt == 0) && (n0 <= 2048);  // wave-uniform
            float inv = rot ? __expf(-0.575646273248511f * (float)(l32 & 15)) : 0.f;
            #pragma unroll
            for (int r = 0; r < 16; r++) {
                int m = m0 + wrow * 64 + mt * 32 + (r & 3) + 8 * (r >> 2) + 4 * half;
                float v = acc[mt][nt][r] + bn;
                if (rot) {
                    float ang = (float)(m & 2047) * inv;
                    float cs, sn;
                    __sincosf(ang, &sn, &cs);
                    float pv = __shfl_xor(v, 16, 64);
                    v = (l32 < 16) ? (v * cs - pv * sn) : (v * cs + pv * sn);
                }
                C[(size_t)m * N + n] = (bf16)v;
            }
        }
    }
}

// gemm2: out = attnb . BT2^T + bias, float out — direct per-r store epilogue
__global__ __launch_bounds__(256) void gemm_out_kernel(const bf16* __restrict__ A, const bf16* __restrict__ BT,
                                                       const float* __restrict__ bias, float* __restrict__ C,
                                                       int M, int N, int K)
{
    GEMM_PROLOGUE_AND_KLOOP

    #pragma unroll
    for (int mt = 0; mt < 2; mt++) {
        #pragma unroll
        for (int nt = 0; nt < 2; nt++) {
            int n = n0 + wcol * 64 + nt * 32 + l32;
            float bn = bias[n];
            #pragma unroll
            for (int r = 0; r < 16; r++) {
                int m = m0 + wrow * 64 + mt * 32 + (r & 3) + 8 * (r >> 2) + 4 * half;
                C[(size_t)m * N + n] = acc[mt][nt][r] + bn;
            }
        }
    }
}

// ---------------- pretile K/V into MFMA fragment order; self-contained (vmT-free) ----------------
__global__ __launch_bounds__(256) void pretile_kernel(const bf16* __restrict__ C1, const int* __restrict__ gidx,
                                                      bf16* __restrict__ KF, bf16* __restrict__ VF)
{
    __shared__ bf16 Vt[64][130];
    const int c = blockIdx.x, b = blockIdx.y;
    const bool isGlob = (c == 32);
    const int tid = threadIdx.x;

    // stage V tile: 64 rows x 128 cols (each thread: 1 row-quarter = 32 cols)
    {
        int row = tid >> 2, cb = (tid & 3) * 32;
        int pos = isGlob ? gidx[b * 64 + row] : (c * 64 + row);
        const bf16* src = C1 + (size_t)(b * 2048 + pos) * 2304 + 2176 + cb;
        #pragma unroll
        for (int k = 0; k < 4; k++)
            *(bf16x8*)&Vt[row][cb + k * 8] = LD8(src + k * 8);
    }
    __syncthreads();

    // KF frags: fi = t*4+ks; direct from C1
    #pragma unroll
    for (int i = 0; i < 4; i++) {
        int sid = tid + i * 256;
        int lane = sid & 63, fi = sid >> 6;
        int l16 = lane & 15, quad = lane >> 4;
        int t = fi >> 2, ks = fi & 3;
        int pos = isGlob ? gidx[b * 64 + t * 16 + l16] : (c * 64 + t * 16 + l16);
        const bf16* src = C1 + (size_t)(b * 2048 + pos) * 2304 + 2048 + ks * 32 + quad * 8;
        *(bf16x8*)&KF[((size_t)(b * 33 + c) * 16 + fi) * 512 + lane * 8] = LD8(src);
    }

    // VF frags: fi = dt*2+ks2; transpose-read from LDS
    #pragma unroll
    for (int i = 0; i < 4; i++) {
        int sid = tid + i * 256;
        int lane = sid & 63, fi = sid >> 6;
        int l16 = lane & 15, quad = lane >> 4;
        int dt = fi >> 1, ks2 = fi & 1;
        int d = dt * 16 + l16;
        bf16x8 v;
        #pragma unroll
        for (int j = 0; j < 8; j++)
            v[j] = Vt[ks2 * 32 + quad * 8 + j][d];
        *(bf16x8*)&VF[((size_t)(b * 33 + c) * 16 + fi) * 512 + lane * 8] = v;
    }
}

#define PSTRIDE 88

// ---------------- attention, first WIN=256 queries (causal): wave-autonomous, pretiled frags ----------------
__device__ __forceinline__ void attn0_body(int bx, int h, int b, bf16* Pw,
                                           const bf16* __restrict__ C1, const bf16* __restrict__ KF,
                                           const bf16* __restrict__ VF, const float* __restrict__ mask,
                                           bf16* __restrict__ attn)
{
    const int tid = threadIdx.x, wv = tid >> 6, lane = tid & 63, quad = lane >> 4, l16 = lane & 15;
    const int q0 = (bx * 4 + wv) * 16;

    bf16x8 af[4];
    const bf16* qbase = C1 + (size_t)(b * 2048 + q0 + l16) * 2304 + h * 128;
    #pragma unroll
    for (int ks = 0; ks < 4; ks++) af[ks] = LD8(qbase + ks * 32 + quad * 8);

    f32x4 m_run = (f32x4){MINV_, MINV_, MINV_, MINV_};
    f32x4 l_run = (f32x4){0.f, 0.f, 0.f, 0.f};
    f32x4 O[8];
    #pragma unroll
    for (int dt = 0; dt < 8; dt++) O[dt] = (f32x4){0.f, 0.f, 0.f, 0.f};

    for (int c = 0; c <= bx; c++) {
        const bf16* KFc = KF + ((size_t)(b * 33 + c) * 16) * 512;
        const bf16* VFc = VF + ((size_t)(b * 33 + c) * 16) * 512;

        f32x4 acc[4];
        #pragma unroll
        for (int t = 0; t < 4; t++) acc[t] = (f32x4){0.f, 0.f, 0.f, 0.f};
        #pragma unroll
        for (int t = 0; t < 4; t++)
            #pragma unroll
            for (int ks = 0; ks < 4; ks++)
                acc[t] = mfma16(af[ks], LD8(KFc + (size_t)(t * 4 + ks) * 512 + lane * 8), acc[t]);

        float sv[4][4];
        #pragma unroll
        for (int t = 0; t < 4; t++) {
            int key = c * 64 + t * 16 + l16;
            float addv = mask[b * 2048 + key];
            #pragma unroll
            for (int r = 0; r < 4; r++) {
                int q = q0 + quad * 4 + r;
                sv[t][r] = (key <= q) ? (acc[t][r] * SCALE_ + addv) : MINV_;
            }
        }

        f32x4 cm;
        #pragma unroll
        for (int r = 0; r < 4; r++) cm[r] = fmaxf(fmaxf(sv[0][r], sv[1][r]), fmaxf(sv[2][r], sv[3][r]));
        #pragma unroll
        for (int ms = 1; ms < 16; ms <<= 1)
            #pragma unroll
            for (int r = 0; r < 4; r++) cm[r] = fmaxf(cm[r], __shfl_xor(cm[r], ms, 64));

        f32x4 nm, alpha;
        #pragma unroll
        for (int r = 0; r < 4; r++) { nm[r] = fmaxf(m_run[r], cm[r]); alpha[r] = __expf(m_run[r] - nm[r]); }

        float pv[4][4];
        f32x4 cs = (f32x4){0.f, 0.f, 0.f, 0.f};
        #pragma unroll
        for (int t = 0; t < 4; t++)
            #pragma unroll
            for (int r = 0; r < 4; r++) {
                pv[t][r] = __expf(sv[t][r] - nm[r]);   // MINV_ underflows to 0
                cs[r] += pv[t][r];
            }
        #pragma unroll
        for (int ms = 1; ms < 16; ms <<= 1)
            #pragma unroll
            for (int r = 0; r < 4; r++) cs[r] += __shfl_xor(cs[r], ms, 64);

        m_run = nm;
        #pragma unroll
        for (int r = 0; r < 4; r++) l_run[r] = l_run[r] * alpha[r] + cs[r];
        #pragma unroll
        for (int dt = 0; dt < 8; dt++)
            #pragma unroll
            for (int r = 0; r < 4; r++) O[dt][r] *= alpha[r];

        #pragma unroll
        for (int t = 0; t < 4; t++)
            #pragma unroll
            for (int r = 0; r < 4; r++)
                Pw[(quad * 4 + r) * PSTRIDE + t * 16 + l16] = (bf16)pv[t][r];
        bf16x8 pa0 = LD8(&Pw[l16 * PSTRIDE + quad * 8]);
        bf16x8 pa1 = LD8(&Pw[l16 * PSTRIDE + 32 + quad * 8]);

        #pragma unroll
        for (int dt = 0; dt < 8; dt++) {
            O[dt] = mfma16(pa0, LD8(VFc + (size_t)(dt * 2 + 0) * 512 + lane * 8), O[dt]);
            O[dt] = mfma16(pa1, LD8(VFc + (size_t)(dt * 2 + 1) * 512 + lane * 8), O[dt]);
        }
    }

    f32x4 invl;
    #pragma unroll
    for (int r = 0; r < 4; r++) invl[r] = 1.0f / l_run[r];
    #pragma unroll
    for (int dt = 0; dt < 8; dt++)
        #pragma unroll
        for (int r = 0; r < 4; r++) {
            int q = q0 + quad * 4 + r;
            attn[(size_t)(b * 2048 + q) * 2048 + h * 128 + dt * 16 + l16] = (bf16)(O[dt][r] * invl[r]);
        }
}

// ---------------- attention steps: barrier-free, wave-autonomous, pretiled frags ----------------
__device__ __forceinline__ void attn_steps_body(int sb, int b, bf16* Pw,
                                                const bf16* __restrict__ C1, const bf16* __restrict__ KF,
                                                const bf16* __restrict__ VF, const float* __restrict__ mask,
                                                const int* __restrict__ gidx, bf16* __restrict__ attn)
{
    const int tid = threadIdx.x, wv = tid >> 6, lane = tid & 63, quad = lane >> 4, l16 = lane & 15;
    const int step = sb * 4 + wv, p = 256 + step;

    bf16x8 af[4];
    const bf16* qrow = C1 + (size_t)(b * 2048 + p) * 2304;
    #pragma unroll
    for (int ks = 0; ks < 4; ks++) af[ks] = LD8(qrow + l16 * 128 + ks * 32 + quad * 8);

    int gix[4];
    #pragma unroll
    for (int t = 0; t < 4; t++) gix[t] = gidx[b * 64 + t * 16 + l16];

    f32x4 m_run = (f32x4){MINV_, MINV_, MINV_, MINV_};
    f32x4 l_run = (f32x4){0.f, 0.f, 0.f, 0.f};
    f32x4 O[8];
    #pragma unroll
    for (int dt = 0; dt < 8; dt++) O[dt] = (f32x4){0.f, 0.f, 0.f, 0.f};

    const int c0 = (step + 1) >> 6;

    for (int iter = 0; iter < 6; iter++) {
        int c;
        bool isGlob = (iter == 0);
        if (isGlob) c = 32;
        else { c = c0 + iter - 1; if (c > 31) break; }

        const bf16* KFc = KF + ((size_t)(b * 33 + c) * 16) * 512;
        const bf16* VFc = VF + ((size_t)(b * 33 + c) * 16) * 512;

        f32x4 acc[4];
        #pragma unroll
        for (int t = 0; t < 4; t++) acc[t] = (f32x4){0.f, 0.f, 0.f, 0.f};
        #pragma unroll
        for (int t = 0; t < 4; t++)
            #pragma unroll
            for (int ks = 0; ks < 4; ks++)
                acc[t] = mfma16(af[ks], LD8(KFc + (size_t)(t * 4 + ks) * 512 + lane * 8), acc[t]);

        float sv[4][4];
        bool vld[4];
        #pragma unroll
        for (int t = 0; t < 4; t++) {
            float addv = 0.f;
            if (isGlob) vld[t] = gix[t] < step;
            else {
                int pos = c * 64 + t * 16 + l16;
                vld[t] = (unsigned)(pos - step - 1) < 256u;
                addv = mask[b * 2048 + pos];
            }
            #pragma unroll
            for (int r = 0; r < 4; r++) sv[t][r] = vld[t] ? (acc[t][r] * SCALE_ + addv) : MINV_;
        }

        f32x4 cm;
        #pragma unroll
        for (int r = 0; r < 4; r++) cm[r] = fmaxf(fmaxf(sv[0][r], sv[1][r]), fmaxf(sv[2][r], sv[3][r]));
        #pragma unroll
        for (int ms = 1; ms < 16; ms <<= 1)
            #pragma unroll
            for (int r = 0; r < 4; r++) cm[r] = fmaxf(cm[r], __shfl_xor(cm[r], ms, 64));

        f32x4 nm, alpha;
        #pragma unroll
        for (int r = 0; r < 4; r++) { nm[r] = fmaxf(m_run[r], cm[r]); alpha[r] = __expf(m_run[r] - nm[r]); }

        float pv[4][4];
        f32x4 cs = (f32x4){0.f, 0.f, 0.f, 0.f};
        #pragma unroll
        for (int t = 0; t < 4; t++)
            #pragma unroll
            for (int r = 0; r < 4; r++) {
                pv[t][r] = vld[t] ? __expf(sv[t][r] - nm[r]) : 0.f;
                cs[r] += pv[t][r];
            }
        #pragma unroll
        for (int ms = 1; ms < 16; ms <<= 1)
            #pragma unroll
            for (int r = 0; r < 4; r++) cs[r] += __shfl_xor(cs[r], ms, 64);

        m_run = nm;
        #pragma unroll
        for (int r = 0; r < 4; r++) l_run[r] = l_run[r] * alpha[r] + cs[r];
        #pragma unroll
        for (int dt = 0; dt < 8; dt++)
            #pragma unroll
            for (int r = 0; r < 4; r++) O[dt][r] *= alpha[r];

        #pragma unroll
        for (int t = 0; t < 4; t++)
            #pragma unroll
            for (int r = 0; r < 4; r++)
                Pw[(quad * 4 + r) * PSTRIDE + t * 16 + l16] = (bf16)pv[t][r];
        bf16x8 pa0 = LD8(&Pw[l16 * PSTRIDE + quad * 8]);
        bf16x8 pa1 = LD8(&Pw[l16 * PSTRIDE + 32 + quad * 8]);

        #pragma unroll
        for (int dt = 0; dt < 8; dt++) {
            O[dt] = mfma16(pa0, LD8(VFc + (size_t)(dt * 2 + 0) * 512 + lane * 8), O[dt]);
            O[dt] = mfma16(pa1, LD8(VFc + (size_t)(dt * 2 + 1) * 512 + lane * 8), O[dt]);
        }
    }

    f32x4 invl;
    #pragma unroll
    for (int r = 0; r < 4; r++) invl[r] = 1.0f / l_run[r];
    #pragma unroll
    for (int dt = 0; dt < 8; dt++)
        #pragma unroll
        for (int r = 0; r < 4; r++) {
            int h = quad * 4 + r;
            attn[(size_t)(b * 2048 + p) * 2048 + h * 128 + dt * 16 + l16] = (bf16)(O[dt][r] * invl[r]);
        }
}

// merged attention launch: x<448 -> steps (sb=x); x>=448 -> attn0 (bi=x-448: bx=bi>>4, h=bi&15)
__global__ __launch_bounds__(256) void attn_all_kernel(const bf16* __restrict__ C1, const bf16* __restrict__ KF,
                                                       const bf16* __restrict__ VF, const float* __restrict__ mask,
                                                       const int* __restrict__ gidx, bf16* __restrict__ attn)
{
    __shared__ __align__(16) bf16 Ps[4 * 16 * PSTRIDE];
    const int wv = threadIdx.x >> 6;
    bf16* Pw = &Ps[wv * (16 * PSTRIDE)];
    if (blockIdx.x < 448) {
        attn_steps_body(blockIdx.x, blockIdx.y, Pw, C1, KF, VF, mask, gidx, attn);
    } else {
        int bi = blockIdx.x - 448;
        attn0_body(bi >> 4, bi & 15, blockIdx.y, Pw, C1, KF, VF, mask, attn);
    }
}

// ---------------- launch ----------------
extern "C" void kernel_launch(void* const* d_in, const int* in_sizes, int n_in,
                              void* d_out, int out_size, void* d_ws, size_t ws_size,
                              hipStream_t stream)
{
    const float* hidden = (const float*)d_in[0];
    const float* amask  = (const float*)d_in[1];
    const int*   gidx   = (const int*)d_in[2];
    const float* Wqkv   = (const float*)d_in[3];
    const float* bqkv   = (const float*)d_in[4];
    const float* Wo     = (const float*)d_in[5];
    const float* bo     = (const float*)d_in[6];

    char* ws = (char*)d_ws;
    size_t off = 0;
    auto take = [&](size_t bytes) -> char* {
        char* p = ws + off;
        off = (off + bytes + 255) & ~(size_t)255;
        return p;
    };
    bf16*  A16   = (bf16*)take(4096ull * 2048 * 2);   // hidden, bf16
    bf16*  BT1   = (bf16*)take(2304ull * 2048 * 2);   // [q cols | k-avg | v-avg]^T
    bf16*  BT2   = (bf16*)take(2048ull * 2048 * 2);   // Wo^T
    bf16*  C1    = (bf16*)take(4096ull * 2304 * 2);   // q(2048) | k_mean(128) | v_mean(128)
    bf16*  KF    = (bf16*)take(2ull * 33 * 16 * 512 * 2);
    bf16*  VF    = (bf16*)take(2ull * 33 * 16 * 512 * 2);
    bf16*  attnb = (bf16*)take(4096ull * 2048 * 2);
    float* bias1 = (float*)take(2304 * 4);

    prep_kernel<<<16897, 256, 0, stream>>>(hidden, A16, Wqkv, BT1, Wo, BT2, bqkv, bias1);

    gemm_rot_kernel<<<dim3(18, 32), 256, 0, stream>>>(A16, BT1, bias1, C1, 4096, 2304, 2048);

    pretile_kernel<<<dim3(33, 2), 256, 0, stream>>>(C1, gidx, KF, VF);

    attn_all_kernel<<<dim3(512, 2), 256, 0, stream>>>(C1, KF, VF, amask, gidx, attnb);

    gemm_out_kernel<<<dim3(16, 32), 256, 0, stream>>>(attnb, BT2, bo, (float*)d_out, 4096, 2048, 2048);

    (void)in_sizes; (void)n_in; (void)out_size; (void)ws_size;
}